// Round 1
// baseline (5912.326 us; speedup 1.0000x reference)
//
#include <hip/hip_runtime.h>

#define N_ROWS 16384
#define OBS    1024
#define HID    2048
#define LAT    256
#define VOCAB  8192
#define HQ     4
#define LN_EPS 1e-5f

static __device__ __forceinline__ unsigned int float_to_ordered(float f) {
    unsigned int u = __float_as_uint(f);
    return (u & 0x80000000u) ? ~u : (u | 0x80000000u);
}

// ---------------------------------------------------------------------------
// Generic 64x64 tiled fp32 GEMM, 256 threads, 4x4 per thread, BK=16.
// A [M,K] row-major, B [K,Nd] row-major, C = A@B + bias.
// SUBA: A := A - A2 (computed on load).  RELU: epilogue relu.
// LOSS: don't write C; accumulate sum((C - X)^2) into *lacc (double).
// C2: optional second copy of the output (for latent -> resid).
// ---------------------------------------------------------------------------
template<bool RELU, bool SUBA, bool LOSS>
__global__ __launch_bounds__(256) void gemm_k(
    const float* __restrict__ A, const float* __restrict__ A2,
    const float* __restrict__ B, const float* __restrict__ bias,
    float* __restrict__ C, float* __restrict__ C2,
    const float* __restrict__ X, double* __restrict__ lacc,
    int M, int Nd, int K)
{
    __shared__ float As[16][68];
    __shared__ float Bs[16][68];
    const int tid = threadIdx.x;
    const int tx = tid & 15, ty = tid >> 4;
    const int n0 = blockIdx.x * 64, m0 = blockIdx.y * 64;

    const int ar  = tid >> 2;         // 0..63 : row within tile (A) / k-row group
    const int akq = (tid & 3) * 4;    // 0,4,8,12 : k offset (float4)
    const int bk  = tid >> 4;         // 0..15 : k row (B)
    const int bn  = (tid & 15) * 4;   // 0..60 : n offset (float4)

    float acc[4][4] = {};

    for (int k0 = 0; k0 < K; k0 += 16) {
        float4 av = *(const float4*)&A[(size_t)(m0 + ar) * K + k0 + akq];
        if (SUBA) {
            float4 a2 = *(const float4*)&A2[(size_t)(m0 + ar) * K + k0 + akq];
            av.x -= a2.x; av.y -= a2.y; av.z -= a2.z; av.w -= a2.w;
        }
        float4 bv = *(const float4*)&B[(size_t)(k0 + bk) * Nd + n0 + bn];
        As[akq + 0][ar] = av.x; As[akq + 1][ar] = av.y;
        As[akq + 2][ar] = av.z; As[akq + 3][ar] = av.w;
        *(float4*)&Bs[bk][bn] = bv;
        __syncthreads();
#pragma unroll
        for (int kk = 0; kk < 16; ++kk) {
            float4 a = *(const float4*)&As[kk][ty * 4];
            float4 b = *(const float4*)&Bs[kk][tx * 4];
            float aa[4] = {a.x, a.y, a.z, a.w};
            float bb[4] = {b.x, b.y, b.z, b.w};
#pragma unroll
            for (int i = 0; i < 4; ++i)
#pragma unroll
                for (int j = 0; j < 4; ++j)
                    acc[i][j] = fmaf(aa[i], bb[j], acc[i][j]);
        }
        __syncthreads();
    }

    if constexpr (LOSS) {
        float lsum = 0.f;
#pragma unroll
        for (int i = 0; i < 4; ++i) {
            const int m = m0 + ty * 4 + i;
#pragma unroll
            for (int j = 0; j < 4; ++j) {
                const int n = n0 + tx * 4 + j;
                float r = acc[i][j] + bias[n] - X[(size_t)m * Nd + n];
                lsum = fmaf(r, r, lsum);
            }
        }
#pragma unroll
        for (int off = 32; off >= 1; off >>= 1) lsum += __shfl_xor(lsum, off);
        __shared__ float red[4];
        if ((tid & 63) == 0) red[tid >> 6] = lsum;
        __syncthreads();
        if (tid == 0)
            atomicAdd(lacc, (double)(red[0] + red[1] + red[2] + red[3]));
    } else {
#pragma unroll
        for (int i = 0; i < 4; ++i) {
            const int m = m0 + ty * 4 + i;
            float4 o;
            float* po = (float*)&o;
#pragma unroll
            for (int j = 0; j < 4; ++j) {
                const int n = n0 + tx * 4 + j;
                float w = acc[i][j] + bias[n];
                if (RELU) w = fmaxf(w, 0.f);
                po[j] = w;
            }
            *(float4*)&C[(size_t)m * Nd + n0 + tx * 4] = o;
            if (C2) *(float4*)&C2[(size_t)m * Nd + n0 + tx * 4] = o;
        }
    }
}

// ---------------------------------------------------------------------------
// LayerNorm + ReLU in place, one block (256 thr) per row of 2048.
// ---------------------------------------------------------------------------
__device__ __forceinline__ float block_reduce_bcast(float v, float* scratch) {
#pragma unroll
    for (int off = 32; off >= 1; off >>= 1) v += __shfl_xor(v, off);
    const int tid = threadIdx.x;
    __syncthreads();
    if ((tid & 63) == 0) scratch[tid >> 6] = v;
    __syncthreads();
    return scratch[0] + scratch[1] + scratch[2] + scratch[3];
}

__global__ __launch_bounds__(256) void ln_relu_k(
    float* __restrict__ h, const float* __restrict__ g, const float* __restrict__ b)
{
    __shared__ float scratch[4];
    const int row = blockIdx.x;
    const int tid = threadIdx.x;
    float* hp = h + (size_t)row * HID + tid * 8;

    float4 v0 = *(const float4*)hp;
    float4 v1 = *(const float4*)(hp + 4);
    float v[8] = {v0.x, v0.y, v0.z, v0.w, v1.x, v1.y, v1.z, v1.w};

    float s = 0.f;
#pragma unroll
    for (int e = 0; e < 8; ++e) s += v[e];
    const float mu = block_reduce_bcast(s, scratch) * (1.f / HID);

    float vs = 0.f;
#pragma unroll
    for (int e = 0; e < 8; ++e) { float d = v[e] - mu; vs = fmaf(d, d, vs); }
    const float var = block_reduce_bcast(vs, scratch) * (1.f / HID);
    const float rs = rsqrtf(var + LN_EPS);

    float4 o0, o1;
    float* po = (float*)&o0;
#pragma unroll
    for (int e = 0; e < 8; ++e) {
        const int col = tid * 8 + e;
        float w = (v[e] - mu) * rs * g[col] + b[col];
        w = fmaxf(w, 0.f);
        if (e < 4) po[e] = w; else ((float*)&o1)[e - 4] = w;
    }
    *(float4*)hp = o0;
    *(float4*)(hp + 4) = o1;
}

// ---------------------------------------------------------------------------
// Codebook squared norms: one wave per row (256 elems -> float4/lane).
// ---------------------------------------------------------------------------
__global__ __launch_bounds__(256) void enorm_k(
    const float* __restrict__ cb, float* __restrict__ enorm)
{
    const int row  = blockIdx.x * 4 + (threadIdx.x >> 6);
    const int lane = threadIdx.x & 63;
    float4 v = *(const float4*)(cb + (size_t)row * LAT + lane * 4);
    float s = v.x * v.x + v.y * v.y + v.z * v.z + v.w * v.w;
#pragma unroll
    for (int off = 32; off >= 1; off >>= 1) s += __shfl_xor(s, off);
    if (lane == 0) enorm[row] = s;
}

__global__ void init_keys_k(unsigned long long* __restrict__ keys) {
    keys[blockIdx.x * 256 + threadIdx.x] = ~0ull;
}

// ---------------------------------------------------------------------------
// Distance + argmin: score[m,v] = ||E_v||^2 - 2 * dot(resid_m, E_v).
// 64-row x 1024-vocab chunk per block (16 vocab tiles of 64), K=256.
// Per-row argmin merged globally via atomicMin on packed (score,idx).
// ---------------------------------------------------------------------------
__global__ __launch_bounds__(256) void dist_argmin_k(
    const float* __restrict__ resid, const float* __restrict__ E,
    const float* __restrict__ enorm, unsigned long long* __restrict__ keys)
{
    __shared__ float As[16][68];
    __shared__ float Bs[16][68];
    const int tid = threadIdx.x;
    const int tx = tid & 15, ty = tid >> 4;
    const int m0  = blockIdx.x * 64;
    const int vc0 = blockIdx.y * 1024;
    const int ar  = tid >> 2;
    const int akq = (tid & 3) * 4;

    unsigned long long best[4] = {~0ull, ~0ull, ~0ull, ~0ull};

    for (int vt = 0; vt < 16; ++vt) {
        const int v0 = vc0 + vt * 64;
        float acc[4][4] = {};
        for (int k0 = 0; k0 < LAT; k0 += 16) {
            float4 av = *(const float4*)&resid[(size_t)(m0 + ar) * LAT + k0 + akq];
            float4 ev = *(const float4*)&E[(size_t)(v0 + ar) * LAT + k0 + akq];
            As[akq + 0][ar] = av.x; As[akq + 1][ar] = av.y;
            As[akq + 2][ar] = av.z; As[akq + 3][ar] = av.w;
            Bs[akq + 0][ar] = ev.x; Bs[akq + 1][ar] = ev.y;
            Bs[akq + 2][ar] = ev.z; Bs[akq + 3][ar] = ev.w;
            __syncthreads();
#pragma unroll
            for (int kk = 0; kk < 16; ++kk) {
                float4 a = *(const float4*)&As[kk][ty * 4];
                float4 b = *(const float4*)&Bs[kk][tx * 4];
                float aa[4] = {a.x, a.y, a.z, a.w};
                float bb[4] = {b.x, b.y, b.z, b.w};
#pragma unroll
                for (int i = 0; i < 4; ++i)
#pragma unroll
                    for (int j = 0; j < 4; ++j)
                        acc[i][j] = fmaf(aa[i], bb[j], acc[i][j]);
            }
            __syncthreads();
        }
#pragma unroll
        for (int j = 0; j < 4; ++j) {
            const int v = v0 + tx * 4 + j;
            const float en = enorm[v];
#pragma unroll
            for (int i = 0; i < 4; ++i) {
                float s = en - 2.0f * acc[i][j];
                unsigned long long key =
                    ((unsigned long long)float_to_ordered(s) << 32) | (unsigned)v;
                if (key < best[i]) best[i] = key;
            }
        }
    }
#pragma unroll
    for (int i = 0; i < 4; ++i) {
#pragma unroll
        for (int mask = 8; mask >= 1; mask >>= 1) {
            unsigned long long o = __shfl_xor(best[i], mask);
            if (o < best[i]) best[i] = o;
        }
        if (tx == 0) atomicMin(&keys[m0 + ty * 4 + i], best[i]);
    }
}

// ---------------------------------------------------------------------------
// Gather chosen code, update residual, accumulate sum(resid_new^2).
// Block of 256 handles 16 rows; one double atomic per block.
// ---------------------------------------------------------------------------
__global__ __launch_bounds__(256) void vq_update_k(
    float* __restrict__ resid, const float* __restrict__ E,
    const unsigned long long* __restrict__ keys, double* __restrict__ acc)
{
    __shared__ float red[4];
    const int tid = threadIdx.x;
    const int base = blockIdx.x * 16;
    float lsum = 0.f;
    for (int r = 0; r < 16; ++r) {
        const int row = base + r;
        const int idx = (int)(keys[row] & 0xFFFFFFFFull);
        const float q = E[(size_t)idx * LAT + tid];
        float v = resid[(size_t)row * LAT + tid] - q;
        resid[(size_t)row * LAT + tid] = v;
        lsum = fmaf(v, v, lsum);
    }
#pragma unroll
    for (int off = 32; off >= 1; off >>= 1) lsum += __shfl_xor(lsum, off);
    if ((tid & 63) == 0) red[tid >> 6] = lsum;
    __syncthreads();
    if (tid == 0) atomicAdd(acc, (double)(red[0] + red[1] + red[2] + red[3]));
}

__global__ void zero_k(double* __restrict__ acc) { acc[threadIdx.x] = 0.0; }

__global__ void finalize_k(const double* __restrict__ acc, float* __restrict__ out) {
    double total = 1.5 * acc[0] / (double)((size_t)N_ROWS * LAT)
                 + 0.5 * acc[1] / (double)((size_t)N_ROWS * OBS);
    out[0] = (float)total;
}

// ---------------------------------------------------------------------------
extern "C" void kernel_launch(void* const* d_in, const int* in_sizes, int n_in,
                              void* d_out, int out_size, void* d_ws, size_t ws_size,
                              hipStream_t stream)
{
    const float* x      = (const float*)d_in[0];
    const float* cb     = (const float*)d_in[1];
    const float* enc_w1 = (const float*)d_in[2];
    const float* enc_b1 = (const float*)d_in[3];
    const float* ln_g   = (const float*)d_in[4];
    const float* ln_b   = (const float*)d_in[5];
    const float* enc_w2 = (const float*)d_in[6];
    const float* enc_b2 = (const float*)d_in[7];
    const float* dec_w1 = (const float*)d_in[8];
    const float* dec_b1 = (const float*)d_in[9];
    const float* dec_w2 = (const float*)d_in[10];
    const float* dec_b2 = (const float*)d_in[11];

    char* ws = (char*)d_ws;
    const size_t H_BYTES = (size_t)N_ROWS * HID * 4;   // 128 MiB (h, reused as dh)
    const size_t L_BYTES = (size_t)N_ROWS * LAT * 4;   // 16 MiB
    float* h      = (float*)(ws);
    float* latent = (float*)(ws + H_BYTES);
    float* resid  = (float*)(ws + H_BYTES + L_BYTES);
    float* enorm  = (float*)(ws + H_BYTES + 2 * L_BYTES);
    unsigned long long* keys =
        (unsigned long long*)(ws + H_BYTES + 2 * L_BYTES + (size_t)HQ * VOCAB * 4);
    double* accs =
        (double*)(ws + H_BYTES + 2 * L_BYTES + (size_t)HQ * VOCAB * 4 + (size_t)N_ROWS * 8);

    zero_k<<<1, 2, 0, stream>>>(accs);
    enorm_k<<<HQ * VOCAB / 4, 256, 0, stream>>>(cb, enorm);

    // encoder GEMM1: h = x @ enc_w1 + b1
    gemm_k<false, false, false><<<dim3(HID / 64, N_ROWS / 64), 256, 0, stream>>>(
        x, nullptr, enc_w1, enc_b1, h, nullptr, nullptr, nullptr, N_ROWS, HID, OBS);
    ln_relu_k<<<N_ROWS, 256, 0, stream>>>(h, ln_g, ln_b);
    // encoder GEMM2: latent = h @ enc_w2 + b2 (also copied into resid)
    gemm_k<false, false, false><<<dim3(LAT / 64, N_ROWS / 64), 256, 0, stream>>>(
        h, nullptr, enc_w2, enc_b2, latent, resid, nullptr, nullptr, N_ROWS, LAT, HID);

    for (int l = 0; l < HQ; ++l) {
        const float* E = cb + (size_t)l * VOCAB * LAT;
        init_keys_k<<<N_ROWS / 256, 256, 0, stream>>>(keys);
        dist_argmin_k<<<dim3(N_ROWS / 64, VOCAB / 1024), 256, 0, stream>>>(
            resid, E, enorm + (size_t)l * VOCAB, keys);
        vq_update_k<<<N_ROWS / 16, 256, 0, stream>>>(resid, E, keys, accs);
    }

    // decoder GEMM3: dh = relu((latent - resid) @ dec_w1 + b1)   (quant = latent - resid)
    gemm_k<true, true, false><<<dim3(HID / 64, N_ROWS / 64), 256, 0, stream>>>(
        latent, resid, dec_w1, dec_b1, h, nullptr, nullptr, nullptr, N_ROWS, HID, LAT);
    // decoder GEMM4 + fused recon loss: sum((dh @ dec_w2 + b2 - x)^2)
    gemm_k<false, false, true><<<dim3(OBS / 64, N_ROWS / 64), 256, 0, stream>>>(
        h, nullptr, dec_w2, dec_b2, nullptr, nullptr, x, accs + 1, N_ROWS, OBS, HID);

    finalize_k<<<1, 1, 0, stream>>>(accs, (float*)d_out);
}

// Round 2
// 2936.880 us; speedup vs baseline: 2.0131x; 2.0131x over previous
//
#include <hip/hip_runtime.h>

#define N_ROWS 16384
#define OBS    1024
#define HID    2048
#define LAT    256
#define VOCAB  8192
#define HQ     4
#define LN_EPS 1e-5f

typedef unsigned short u16;
typedef __bf16 bf16x8 __attribute__((ext_vector_type(8)));
typedef float  f32x4  __attribute__((ext_vector_type(4)));

static __device__ __forceinline__ unsigned int float_to_ordered(float f) {
    unsigned int u = __float_as_uint(f);
    return (u & 0x80000000u) ? ~u : (u | 0x80000000u);
}

// fp32 -> bf16 round-to-nearest-even (bit pattern as u16)
static __device__ __forceinline__ u16 f2bf(float f) {
    unsigned int u = __float_as_uint(f);
    unsigned int r = u + 0x7FFFu + ((u >> 16) & 1u);
    return (u16)(r >> 16);
}

#define GL2LDS(gp, lp) __builtin_amdgcn_global_load_lds( \
    (const __attribute__((address_space(1))) void*)(gp), \
    (__attribute__((address_space(3))) void*)(lp), 16, 0, 0)

// ---------------------------------------------------------------------------
// Generic 64x64 tiled fp32 GEMM, 256 threads, 4x4 per thread, BK=16.
// (unchanged from round 1 — GEMM1/2/3/4)
// ---------------------------------------------------------------------------
template<bool RELU, bool SUBA, bool LOSS>
__global__ __launch_bounds__(256) void gemm_k(
    const float* __restrict__ A, const float* __restrict__ A2,
    const float* __restrict__ B, const float* __restrict__ bias,
    float* __restrict__ C, float* __restrict__ C2,
    const float* __restrict__ X, double* __restrict__ lacc,
    int M, int Nd, int K)
{
    __shared__ float As[16][68];
    __shared__ float Bs[16][68];
    const int tid = threadIdx.x;
    const int tx = tid & 15, ty = tid >> 4;
    const int n0 = blockIdx.x * 64, m0 = blockIdx.y * 64;

    const int ar  = tid >> 2;
    const int akq = (tid & 3) * 4;
    const int bk  = tid >> 4;
    const int bn  = (tid & 15) * 4;

    float acc[4][4] = {};

    for (int k0 = 0; k0 < K; k0 += 16) {
        float4 av = *(const float4*)&A[(size_t)(m0 + ar) * K + k0 + akq];
        if (SUBA) {
            float4 a2 = *(const float4*)&A2[(size_t)(m0 + ar) * K + k0 + akq];
            av.x -= a2.x; av.y -= a2.y; av.z -= a2.z; av.w -= a2.w;
        }
        float4 bv = *(const float4*)&B[(size_t)(k0 + bk) * Nd + n0 + bn];
        As[akq + 0][ar] = av.x; As[akq + 1][ar] = av.y;
        As[akq + 2][ar] = av.z; As[akq + 3][ar] = av.w;
        *(float4*)&Bs[bk][bn] = bv;
        __syncthreads();
#pragma unroll
        for (int kk = 0; kk < 16; ++kk) {
            float4 a = *(const float4*)&As[kk][ty * 4];
            float4 b = *(const float4*)&Bs[kk][tx * 4];
            float aa[4] = {a.x, a.y, a.z, a.w};
            float bb[4] = {b.x, b.y, b.z, b.w};
#pragma unroll
            for (int i = 0; i < 4; ++i)
#pragma unroll
                for (int j = 0; j < 4; ++j)
                    acc[i][j] = fmaf(aa[i], bb[j], acc[i][j]);
        }
        __syncthreads();
    }

    if constexpr (LOSS) {
        float lsum = 0.f;
#pragma unroll
        for (int i = 0; i < 4; ++i) {
            const int m = m0 + ty * 4 + i;
#pragma unroll
            for (int j = 0; j < 4; ++j) {
                const int n = n0 + tx * 4 + j;
                float r = acc[i][j] + bias[n] - X[(size_t)m * Nd + n];
                lsum = fmaf(r, r, lsum);
            }
        }
#pragma unroll
        for (int off = 32; off >= 1; off >>= 1) lsum += __shfl_xor(lsum, off);
        __shared__ float red[4];
        if ((tid & 63) == 0) red[tid >> 6] = lsum;
        __syncthreads();
        if (tid == 0)
            atomicAdd(lacc, (double)(red[0] + red[1] + red[2] + red[3]));
    } else {
#pragma unroll
        for (int i = 0; i < 4; ++i) {
            const int m = m0 + ty * 4 + i;
            float4 o;
            float* po = (float*)&o;
#pragma unroll
            for (int j = 0; j < 4; ++j) {
                const int n = n0 + tx * 4 + j;
                float w = acc[i][j] + bias[n];
                if (RELU) w = fmaxf(w, 0.f);
                po[j] = w;
            }
            *(float4*)&C[(size_t)m * Nd + n0 + tx * 4] = o;
            if (C2) *(float4*)&C2[(size_t)m * Nd + n0 + tx * 4] = o;
        }
    }
}

// ---------------------------------------------------------------------------
// LayerNorm + ReLU in place (unchanged)
// ---------------------------------------------------------------------------
__device__ __forceinline__ float block_reduce_bcast(float v, float* scratch) {
#pragma unroll
    for (int off = 32; off >= 1; off >>= 1) v += __shfl_xor(v, off);
    const int tid = threadIdx.x;
    __syncthreads();
    if ((tid & 63) == 0) scratch[tid >> 6] = v;
    __syncthreads();
    return scratch[0] + scratch[1] + scratch[2] + scratch[3];
}

__global__ __launch_bounds__(256) void ln_relu_k(
    float* __restrict__ h, const float* __restrict__ g, const float* __restrict__ b)
{
    __shared__ float scratch[4];
    const int row = blockIdx.x;
    const int tid = threadIdx.x;
    float* hp = h + (size_t)row * HID + tid * 8;

    float4 v0 = *(const float4*)hp;
    float4 v1 = *(const float4*)(hp + 4);
    float v[8] = {v0.x, v0.y, v0.z, v0.w, v1.x, v1.y, v1.z, v1.w};

    float s = 0.f;
#pragma unroll
    for (int e = 0; e < 8; ++e) s += v[e];
    const float mu = block_reduce_bcast(s, scratch) * (1.f / HID);

    float vs = 0.f;
#pragma unroll
    for (int e = 0; e < 8; ++e) { float d = v[e] - mu; vs = fmaf(d, d, vs); }
    const float var = block_reduce_bcast(vs, scratch) * (1.f / HID);
    const float rs = rsqrtf(var + LN_EPS);

    float4 o0, o1;
#pragma unroll
    for (int e = 0; e < 8; ++e) {
        const int col = tid * 8 + e;
        float w = (v[e] - mu) * rs * g[col] + b[col];
        w = fmaxf(w, 0.f);
        if (e < 4) ((float*)&o0)[e] = w; else ((float*)&o1)[e - 4] = w;
    }
    *(float4*)hp = o0;
    *(float4*)(hp + 4) = o1;
}

// ---------------------------------------------------------------------------
// Codebook squared norms from fp32 codebook (exact)
// ---------------------------------------------------------------------------
__global__ __launch_bounds__(256) void enorm_k(
    const float* __restrict__ cb, float* __restrict__ enorm)
{
    const int row  = blockIdx.x * 4 + (threadIdx.x >> 6);
    const int lane = threadIdx.x & 63;
    float4 v = *(const float4*)(cb + (size_t)row * LAT + lane * 4);
    float s = v.x * v.x + v.y * v.y + v.z * v.z + v.w * v.w;
#pragma unroll
    for (int off = 32; off >= 1; off >>= 1) s += __shfl_xor(s, off);
    if (lane == 0) enorm[row] = s;
}

__global__ void init_keys_k(unsigned long long* __restrict__ keys) {
    keys[blockIdx.x * 256 + threadIdx.x] = ~0ull;
}

// fp32 -> bf16 bulk convert (4 elems/thread)
__global__ __launch_bounds__(256) void f2bf_k(
    const float* __restrict__ in, u16* __restrict__ out)
{
    size_t i = ((size_t)blockIdx.x * 256 + threadIdx.x) * 4;
    float4 v = *(const float4*)(in + i);
    ushort4 o;
    o.x = f2bf(v.x); o.y = f2bf(v.y); o.z = f2bf(v.z); o.w = f2bf(v.w);
    *(ushort4*)(out + i) = o;
}

// ---------------------------------------------------------------------------
// Distance + argmin via bf16 MFMA.
// score[m,v] = ||E_v||^2_fp32 - 2 * mfma_dot_bf16(resid_m, E_v)
// 128x128 tile per block (256 thr = 4 waves, 2x2 wave grid, 4x4 MFMA tiles of
// 16x16x32 each). A and codebook both row-major K-contiguous (A @ B^T form).
// global_load_lds width=16 with XOR-swizzled LDS (swizzle applied to the
// GLOBAL source address since the LDS dest is forced to base + lane*16).
// ---------------------------------------------------------------------------
__global__ __launch_bounds__(256) void dist_mfma_k(
    const u16* __restrict__ Abf, const u16* __restrict__ Bbf,
    const float* __restrict__ enorm, unsigned long long* __restrict__ keys)
{
    __shared__ u16 As[128 * 64];
    __shared__ u16 Bs[128 * 64];
    __shared__ unsigned long long shk[128][2];

    const int tid  = threadIdx.x;
    const int wv   = tid >> 6, lane = tid & 63;
    const int wm   = wv & 1,   wn   = wv >> 1;
    const int m_   = lane & 15, g   = lane >> 4;
    const int m0   = blockIdx.x * 128;
    const int n0   = blockIdx.y * 128;

    f32x4 acc[4][4];
#pragma unroll
    for (int i = 0; i < 4; ++i)
#pragma unroll
        for (int j = 0; j < 4; ++j)
            acc[i][j] = f32x4{0.f, 0.f, 0.f, 0.f};

    const u16* Ablk = Abf + (size_t)m0 * LAT;
    const u16* Bblk = Bbf + (size_t)n0 * LAT;

    for (int k0 = 0; k0 < LAT; k0 += 64) {
#pragma unroll
        for (int c = 0; c < 4; ++c) {
            const int ci = (wv * 4 + c) * 64 + lane;     // 16B-chunk index 0..1023
            const int r  = ci >> 3;                       // tile row 0..127
            const int cc = ci & 7;                        // dest chunk col 0..7
            const int kc = (cc ^ (r & 7)) << 3;           // swizzled source k-offset
            GL2LDS(Ablk + (size_t)r * LAT + k0 + kc, As + (wv * 4 + c) * 512);
            GL2LDS(Bblk + (size_t)r * LAT + k0 + kc, Bs + (wv * 4 + c) * 512);
        }
        __syncthreads();
#pragma unroll
        for (int ks = 0; ks < 2; ++ks) {
            const int ccw = ks * 4 + g;                   // wanted chunk col
            const int sw  = (ccw ^ (m_ & 7)) << 3;        // swizzled elem offset
            bf16x8 af[4], bfr[4];
#pragma unroll
            for (int t = 0; t < 4; ++t) {
                af[t]  = *(const bf16x8*)&As[(wm * 64 + t * 16 + m_) * 64 + sw];
                bfr[t] = *(const bf16x8*)&Bs[(wn * 64 + t * 16 + m_) * 64 + sw];
            }
#pragma unroll
            for (int mi = 0; mi < 4; ++mi)
#pragma unroll
                for (int ni = 0; ni < 4; ++ni)
                    acc[mi][ni] = __builtin_amdgcn_mfma_f32_16x16x32_bf16(
                        af[mi], bfr[ni], acc[mi][ni], 0, 0, 0);
        }
        __syncthreads();
    }

    float en[4];
#pragma unroll
    for (int ni = 0; ni < 4; ++ni) en[ni] = enorm[n0 + wn * 64 + ni * 16 + m_];

#pragma unroll
    for (int mi = 0; mi < 4; ++mi) {
#pragma unroll
        for (int j = 0; j < 4; ++j) {
            unsigned long long best = ~0ull;
#pragma unroll
            for (int ni = 0; ni < 4; ++ni) {
                const int v = n0 + wn * 64 + ni * 16 + m_;
                const float s = en[ni] - 2.0f * acc[mi][ni][j];
                unsigned long long key =
                    ((unsigned long long)float_to_ordered(s) << 32) | (unsigned)v;
                best = key < best ? key : best;
            }
#pragma unroll
            for (int mask = 1; mask <= 8; mask <<= 1) {
                unsigned long long o = __shfl_xor(best, mask);
                best = o < best ? o : best;
            }
            if (m_ == 0) shk[wm * 64 + mi * 16 + g * 4 + j][wn] = best;
        }
    }
    __syncthreads();
    if (tid < 128) {
        unsigned long long a = shk[tid][0], b = shk[tid][1];
        atomicMin(&keys[m0 + tid], a < b ? a : b);
    }
}

// ---------------------------------------------------------------------------
// Gather chosen code (fp32, exact), update residual, write bf16 residual for
// the next level's distance pass, accumulate sum(resid_new^2).
// ---------------------------------------------------------------------------
__global__ __launch_bounds__(256) void vq_update_k(
    float* __restrict__ resid, u16* __restrict__ rbf,
    const float* __restrict__ E,
    const unsigned long long* __restrict__ keys, double* __restrict__ acc)
{
    __shared__ float red[4];
    const int tid = threadIdx.x;
    const int base = blockIdx.x * 16;
    float lsum = 0.f;
    for (int r = 0; r < 16; ++r) {
        const int row = base + r;
        const int idx = (int)(keys[row] & 0xFFFFFFFFull);
        const float q = E[(size_t)idx * LAT + tid];
        float v = resid[(size_t)row * LAT + tid] - q;
        resid[(size_t)row * LAT + tid] = v;
        rbf[(size_t)row * LAT + tid] = f2bf(v);
        lsum = fmaf(v, v, lsum);
    }
#pragma unroll
    for (int off = 32; off >= 1; off >>= 1) lsum += __shfl_xor(lsum, off);
    if ((tid & 63) == 0) red[tid >> 6] = lsum;
    __syncthreads();
    if (tid == 0) atomicAdd(acc, (double)(red[0] + red[1] + red[2] + red[3]));
}

__global__ void zero_k(double* __restrict__ acc) { acc[threadIdx.x] = 0.0; }

__global__ void finalize_k(const double* __restrict__ acc, float* __restrict__ out) {
    double total = 1.5 * acc[0] / (double)((size_t)N_ROWS * LAT)
                 + 0.5 * acc[1] / (double)((size_t)N_ROWS * OBS);
    out[0] = (float)total;
}

// ---------------------------------------------------------------------------
extern "C" void kernel_launch(void* const* d_in, const int* in_sizes, int n_in,
                              void* d_out, int out_size, void* d_ws, size_t ws_size,
                              hipStream_t stream)
{
    const float* x      = (const float*)d_in[0];
    const float* cb     = (const float*)d_in[1];
    const float* enc_w1 = (const float*)d_in[2];
    const float* enc_b1 = (const float*)d_in[3];
    const float* ln_g   = (const float*)d_in[4];
    const float* ln_b   = (const float*)d_in[5];
    const float* enc_w2 = (const float*)d_in[6];
    const float* enc_b2 = (const float*)d_in[7];
    const float* dec_w1 = (const float*)d_in[8];
    const float* dec_b1 = (const float*)d_in[9];
    const float* dec_w2 = (const float*)d_in[10];
    const float* dec_b2 = (const float*)d_in[11];

    char* ws = (char*)d_ws;
    const size_t H_BYTES  = (size_t)N_ROWS * HID * 4;          // 128 MiB
    const size_t L_BYTES  = (size_t)N_ROWS * LAT * 4;          // 16 MiB
    const size_t CB_BYTES = (size_t)HQ * VOCAB * LAT * 2;      // 16 MiB (bf16)

    float* h      = (float*)(ws);
    // VQ-phase scratch overlapping h (h is dead between GEMM2 and GEMM3):
    u16*   cbb    = (u16*)(ws);                                 // bf16 codebooks
    u16*   rbf    = (u16*)(ws + CB_BYTES);                      // bf16 residual
    float* latent = (float*)(ws + H_BYTES);
    float* resid  = (float*)(ws + H_BYTES + L_BYTES);
    float* enorm  = (float*)(ws + H_BYTES + 2 * L_BYTES);
    unsigned long long* keys =
        (unsigned long long*)(ws + H_BYTES + 2 * L_BYTES + (size_t)HQ * VOCAB * 4);
    double* accs =
        (double*)(ws + H_BYTES + 2 * L_BYTES + (size_t)HQ * VOCAB * 4 + (size_t)N_ROWS * 8);

    zero_k<<<1, 2, 0, stream>>>(accs);
    enorm_k<<<HQ * VOCAB / 4, 256, 0, stream>>>(cb, enorm);

    // encoder
    gemm_k<false, false, false><<<dim3(HID / 64, N_ROWS / 64), 256, 0, stream>>>(
        x, nullptr, enc_w1, enc_b1, h, nullptr, nullptr, nullptr, N_ROWS, HID, OBS);
    ln_relu_k<<<N_ROWS, 256, 0, stream>>>(h, ln_g, ln_b);
    gemm_k<false, false, false><<<dim3(LAT / 64, N_ROWS / 64), 256, 0, stream>>>(
        h, nullptr, enc_w2, enc_b2, latent, resid, nullptr, nullptr, N_ROWS, LAT, HID);

    // bf16 copies for the MFMA distance pass (h region is now free)
    f2bf_k<<<(int)(HQ * VOCAB * LAT / 1024), 256, 0, stream>>>(cb, cbb);
    f2bf_k<<<(int)((size_t)N_ROWS * LAT / 1024), 256, 0, stream>>>(resid, rbf);

    for (int l = 0; l < HQ; ++l) {
        init_keys_k<<<N_ROWS / 256, 256, 0, stream>>>(keys);
        dist_mfma_k<<<dim3(N_ROWS / 128, VOCAB / 128), 256, 0, stream>>>(
            rbf, cbb + (size_t)l * VOCAB * LAT, enorm + (size_t)l * VOCAB, keys);
        vq_update_k<<<N_ROWS / 16, 256, 0, stream>>>(
            resid, rbf, cb + (size_t)l * VOCAB * LAT, keys, accs);
    }

    // decoder (quant = latent - resid)
    gemm_k<true, true, false><<<dim3(HID / 64, N_ROWS / 64), 256, 0, stream>>>(
        latent, resid, dec_w1, dec_b1, h, nullptr, nullptr, nullptr, N_ROWS, HID, LAT);
    gemm_k<false, false, true><<<dim3(OBS / 64, N_ROWS / 64), 256, 0, stream>>>(
        h, nullptr, dec_w2, dec_b2, nullptr, nullptr, x, accs + 1, N_ROWS, OBS, HID);

    finalize_k<<<1, 1, 0, stream>>>(accs, (float*)d_out);
}

// Round 3
// 1026.118 us; speedup vs baseline: 5.7618x; 2.8621x over previous
//
#include <hip/hip_runtime.h>

#define N_ROWS 16384
#define OBS    1024
#define HID    2048
#define LAT    256
#define VOCAB  8192
#define HQ     4
#define LN_EPS 1e-5f

typedef unsigned short u16;
typedef unsigned long long u64;
typedef __bf16 bf16x8 __attribute__((ext_vector_type(8)));
typedef float  f32x4  __attribute__((ext_vector_type(4)));

static __device__ __forceinline__ unsigned int float_to_ordered(float f) {
    unsigned int u = __float_as_uint(f);
    return (u & 0x80000000u) ? ~u : (u | 0x80000000u);
}
// fp32 -> bf16 round-to-nearest-even
static __device__ __forceinline__ u16 f2bf(float f) {
    unsigned int u = __float_as_uint(f);
    unsigned int r = u + 0x7FFFu + ((u >> 16) & 1u);
    return (u16)(r >> 16);
}
static __device__ __forceinline__ float bf2f(u16 u) {
    return __uint_as_float((unsigned int)u << 16);
}

#define GL2LDS(gp, lp) __builtin_amdgcn_global_load_lds( \
    (const __attribute__((address_space(1))) void*)(gp), \
    (__attribute__((address_space(3))) void*)(lp), 16, 0, 0)

// ---------------------------------------------------------------------------
// bf16 MFMA GEMM, 128x128 tile, C = A @ B^T + bias.
// A [M,K] bf16 row-major, B [N,K] bf16 row-major (pre-transposed weights).
// EPI 0: store bf16 C.  1: relu + store bf16 C.
//     2: store fp32 latent + fp32 resid + bf16 rbf (all = C).
//     3: loss — accumulate sum((C - X)^2) into *lacc, no store.
// Same verified K-loop / swizzle as dist_mfma_k.
// ---------------------------------------------------------------------------
template<int EPI>
__global__ __launch_bounds__(256) void mfma_gemm_k(
    const u16* __restrict__ Abf, const u16* __restrict__ Bbf,
    const float* __restrict__ bias,
    u16* __restrict__ Cbf,
    float* __restrict__ lat, float* __restrict__ resid, u16* __restrict__ rbf,
    const float* __restrict__ X, double* __restrict__ lacc,
    int K, int Nd)
{
    __shared__ u16 As[128 * 64];
    __shared__ u16 Bs[128 * 64];

    const int tid  = threadIdx.x;
    const int wv   = tid >> 6, lane = tid & 63;
    const int wm   = wv & 1,   wn   = wv >> 1;
    const int m_   = lane & 15, g   = lane >> 4;
    const int m0   = blockIdx.x * 128;
    const int n0   = blockIdx.y * 128;

    f32x4 acc[4][4];
#pragma unroll
    for (int i = 0; i < 4; ++i)
#pragma unroll
        for (int j = 0; j < 4; ++j)
            acc[i][j] = f32x4{0.f, 0.f, 0.f, 0.f};

    const u16* Ablk = Abf + (size_t)m0 * K;
    const u16* Bblk = Bbf + (size_t)n0 * K;

    for (int k0 = 0; k0 < K; k0 += 64) {
#pragma unroll
        for (int c = 0; c < 4; ++c) {
            const int ci = (wv * 4 + c) * 64 + lane;
            const int r  = ci >> 3;
            const int cc = ci & 7;
            const int kc = (cc ^ (r & 7)) << 3;
            GL2LDS(Ablk + (size_t)r * K + k0 + kc, As + (wv * 4 + c) * 512);
            GL2LDS(Bblk + (size_t)r * K + k0 + kc, Bs + (wv * 4 + c) * 512);
        }
        __syncthreads();
#pragma unroll
        for (int ks = 0; ks < 2; ++ks) {
            const int ccw = ks * 4 + g;
            const int sw  = (ccw ^ (m_ & 7)) << 3;
            bf16x8 af[4], bfr[4];
#pragma unroll
            for (int t = 0; t < 4; ++t) {
                af[t]  = *(const bf16x8*)&As[(wm * 64 + t * 16 + m_) * 64 + sw];
                bfr[t] = *(const bf16x8*)&Bs[(wn * 64 + t * 16 + m_) * 64 + sw];
            }
#pragma unroll
            for (int mi = 0; mi < 4; ++mi)
#pragma unroll
                for (int ni = 0; ni < 4; ++ni)
                    acc[mi][ni] = __builtin_amdgcn_mfma_f32_16x16x32_bf16(
                        af[mi], bfr[ni], acc[mi][ni], 0, 0, 0);
        }
        __syncthreads();
    }

    float bs[4];
#pragma unroll
    for (int ni = 0; ni < 4; ++ni) bs[ni] = bias[n0 + wn * 64 + ni * 16 + m_];

    if constexpr (EPI == 3) {
        float lsum = 0.f;
#pragma unroll
        for (int mi = 0; mi < 4; ++mi)
#pragma unroll
            for (int j = 0; j < 4; ++j) {
                const int row = m0 + wm * 64 + mi * 16 + g * 4 + j;
#pragma unroll
                for (int ni = 0; ni < 4; ++ni) {
                    const int col = n0 + wn * 64 + ni * 16 + m_;
                    float r = acc[mi][ni][j] + bs[ni] - X[(size_t)row * Nd + col];
                    lsum = fmaf(r, r, lsum);
                }
            }
#pragma unroll
        for (int off = 32; off >= 1; off >>= 1) lsum += __shfl_xor(lsum, off);
        __shared__ float red[4];
        if (lane == 0) red[wv] = lsum;
        __syncthreads();
        if (tid == 0)
            atomicAdd(lacc, (double)(red[0] + red[1] + red[2] + red[3]));
    } else {
#pragma unroll
        for (int mi = 0; mi < 4; ++mi)
#pragma unroll
            for (int j = 0; j < 4; ++j) {
                const int row = m0 + wm * 64 + mi * 16 + g * 4 + j;
#pragma unroll
                for (int ni = 0; ni < 4; ++ni) {
                    const int col = n0 + wn * 64 + ni * 16 + m_;
                    float v = acc[mi][ni][j] + bs[ni];
                    if constexpr (EPI == 1) v = fmaxf(v, 0.f);
                    if constexpr (EPI == 2) {
                        lat  [(size_t)row * Nd + col] = v;
                        resid[(size_t)row * Nd + col] = v;
                        rbf  [(size_t)row * Nd + col] = f2bf(v);
                    } else {
                        Cbf[(size_t)row * Nd + col] = f2bf(v);
                    }
                }
            }
    }
}

// ---------------------------------------------------------------------------
// Transpose + convert weights: W fp32 [K,N] -> Wt bf16 [N,K]
// ---------------------------------------------------------------------------
__global__ __launch_bounds__(256) void tpose_bf_k(
    const float* __restrict__ W, u16* __restrict__ Wt, int K, int N)
{
    __shared__ u16 t[32][33];
    const int lx = threadIdx.x & 31, ly = threadIdx.x >> 5;
    const int n0 = blockIdx.x * 32, k0 = blockIdx.y * 32;
#pragma unroll
    for (int i = 0; i < 4; ++i)
        t[ly + 8 * i][lx] = f2bf(W[(size_t)(k0 + ly + 8 * i) * N + n0 + lx]);
    __syncthreads();
#pragma unroll
    for (int i = 0; i < 4; ++i)
        Wt[(size_t)(n0 + ly + 8 * i) * K + k0 + lx] = t[lx][ly + 8 * i];
}

// ---------------------------------------------------------------------------
// LayerNorm + ReLU in place on bf16 h (fp32 math), one block per row of 2048.
// ---------------------------------------------------------------------------
__device__ __forceinline__ float block_reduce_bcast(float v, float* scratch) {
#pragma unroll
    for (int off = 32; off >= 1; off >>= 1) v += __shfl_xor(v, off);
    const int tid = threadIdx.x;
    __syncthreads();
    if ((tid & 63) == 0) scratch[tid >> 6] = v;
    __syncthreads();
    return scratch[0] + scratch[1] + scratch[2] + scratch[3];
}

__global__ __launch_bounds__(256) void ln_relu_bf_k(
    u16* __restrict__ h, const float* __restrict__ g, const float* __restrict__ b)
{
    __shared__ float scratch[4];
    const int tid = threadIdx.x;
    u16* hp = h + (size_t)blockIdx.x * HID + tid * 8;

    ushort4 r0 = *(const ushort4*)hp;
    ushort4 r1 = *(const ushort4*)(hp + 4);
    float v[8] = {bf2f(r0.x), bf2f(r0.y), bf2f(r0.z), bf2f(r0.w),
                  bf2f(r1.x), bf2f(r1.y), bf2f(r1.z), bf2f(r1.w)};

    float s = 0.f;
#pragma unroll
    for (int e = 0; e < 8; ++e) s += v[e];
    const float mu = block_reduce_bcast(s, scratch) * (1.f / HID);

    float vs = 0.f;
#pragma unroll
    for (int e = 0; e < 8; ++e) { float d = v[e] - mu; vs = fmaf(d, d, vs); }
    const float var = block_reduce_bcast(vs, scratch) * (1.f / HID);
    const float rs = rsqrtf(var + LN_EPS);

    ushort4 o0, o1;
#pragma unroll
    for (int e = 0; e < 8; ++e) {
        const int col = tid * 8 + e;
        float w = (v[e] - mu) * rs * g[col] + b[col];
        w = fmaxf(w, 0.f);
        u16 bb = f2bf(w);
        if (e < 4) ((u16*)&o0)[e] = bb; else ((u16*)&o1)[e - 4] = bb;
    }
    *(ushort4*)hp = o0;
    *(ushort4*)(hp + 4) = o1;
}

// ---------------------------------------------------------------------------
// Codebook squared norms from fp32 codebook (exact)
// ---------------------------------------------------------------------------
__global__ __launch_bounds__(256) void enorm_k(
    const float* __restrict__ cb, float* __restrict__ enorm)
{
    const int row  = blockIdx.x * 4 + (threadIdx.x >> 6);
    const int lane = threadIdx.x & 63;
    float4 v = *(const float4*)(cb + (size_t)row * LAT + lane * 4);
    float s = v.x * v.x + v.y * v.y + v.z * v.z + v.w * v.w;
#pragma unroll
    for (int off = 32; off >= 1; off >>= 1) s += __shfl_xor(s, off);
    if (lane == 0) enorm[row] = s;
}

__global__ void init_keys_k(u64* __restrict__ keys) {
    keys[blockIdx.x * 256 + threadIdx.x] = ~0ull;
}

// fp32 -> bf16 bulk convert (4 elems/thread)
__global__ __launch_bounds__(256) void f2bf_k(
    const float* __restrict__ in, u16* __restrict__ out)
{
    size_t i = ((size_t)blockIdx.x * 256 + threadIdx.x) * 4;
    float4 v = *(const float4*)(in + i);
    ushort4 o;
    o.x = f2bf(v.x); o.y = f2bf(v.y); o.z = f2bf(v.z); o.w = f2bf(v.w);
    *(ushort4*)(out + i) = o;
}

// quant = latent - resid -> bf16
__global__ __launch_bounds__(256) void quant_bf_k(
    const float* __restrict__ lat, const float* __restrict__ resid,
    u16* __restrict__ qbf)
{
    size_t i = ((size_t)blockIdx.x * 256 + threadIdx.x) * 4;
    float4 a = *(const float4*)(lat + i);
    float4 b = *(const float4*)(resid + i);
    ushort4 o;
    o.x = f2bf(a.x - b.x); o.y = f2bf(a.y - b.y);
    o.z = f2bf(a.z - b.z); o.w = f2bf(a.w - b.w);
    *(ushort4*)(qbf + i) = o;
}

// ---------------------------------------------------------------------------
// Distance + argmin via bf16 MFMA (unchanged, correctness-verified round 2)
// ---------------------------------------------------------------------------
__global__ __launch_bounds__(256) void dist_mfma_k(
    const u16* __restrict__ Abf, const u16* __restrict__ Bbf,
    const float* __restrict__ enorm, u64* __restrict__ keys)
{
    __shared__ u16 As[128 * 64];
    __shared__ u16 Bs[128 * 64];
    __shared__ u64 shk[128][2];

    const int tid  = threadIdx.x;
    const int wv   = tid >> 6, lane = tid & 63;
    const int wm   = wv & 1,   wn   = wv >> 1;
    const int m_   = lane & 15, g   = lane >> 4;
    const int m0   = blockIdx.x * 128;
    const int n0   = blockIdx.y * 128;

    f32x4 acc[4][4];
#pragma unroll
    for (int i = 0; i < 4; ++i)
#pragma unroll
        for (int j = 0; j < 4; ++j)
            acc[i][j] = f32x4{0.f, 0.f, 0.f, 0.f};

    const u16* Ablk = Abf + (size_t)m0 * LAT;
    const u16* Bblk = Bbf + (size_t)n0 * LAT;

    for (int k0 = 0; k0 < LAT; k0 += 64) {
#pragma unroll
        for (int c = 0; c < 4; ++c) {
            const int ci = (wv * 4 + c) * 64 + lane;
            const int r  = ci >> 3;
            const int cc = ci & 7;
            const int kc = (cc ^ (r & 7)) << 3;
            GL2LDS(Ablk + (size_t)r * LAT + k0 + kc, As + (wv * 4 + c) * 512);
            GL2LDS(Bblk + (size_t)r * LAT + k0 + kc, Bs + (wv * 4 + c) * 512);
        }
        __syncthreads();
#pragma unroll
        for (int ks = 0; ks < 2; ++ks) {
            const int ccw = ks * 4 + g;
            const int sw  = (ccw ^ (m_ & 7)) << 3;
            bf16x8 af[4], bfr[4];
#pragma unroll
            for (int t = 0; t < 4; ++t) {
                af[t]  = *(const bf16x8*)&As[(wm * 64 + t * 16 + m_) * 64 + sw];
                bfr[t] = *(const bf16x8*)&Bs[(wn * 64 + t * 16 + m_) * 64 + sw];
            }
#pragma unroll
            for (int mi = 0; mi < 4; ++mi)
#pragma unroll
                for (int ni = 0; ni < 4; ++ni)
                    acc[mi][ni] = __builtin_amdgcn_mfma_f32_16x16x32_bf16(
                        af[mi], bfr[ni], acc[mi][ni], 0, 0, 0);
        }
        __syncthreads();
    }

    float en[4];
#pragma unroll
    for (int ni = 0; ni < 4; ++ni) en[ni] = enorm[n0 + wn * 64 + ni * 16 + m_];

#pragma unroll
    for (int mi = 0; mi < 4; ++mi) {
#pragma unroll
        for (int j = 0; j < 4; ++j) {
            u64 best = ~0ull;
#pragma unroll
            for (int ni = 0; ni < 4; ++ni) {
                const int v = n0 + wn * 64 + ni * 16 + m_;
                const float s = en[ni] - 2.0f * acc[mi][ni][j];
                u64 key = ((u64)float_to_ordered(s) << 32) | (unsigned)v;
                best = key < best ? key : best;
            }
#pragma unroll
            for (int mask = 1; mask <= 8; mask <<= 1) {
                u64 o = __shfl_xor(best, mask);
                best = o < best ? o : best;
            }
            if (m_ == 0) shk[wm * 64 + mi * 16 + g * 4 + j][wn] = best;
        }
    }
    __syncthreads();
    if (tid < 128) {
        u64 a = shk[tid][0], b = shk[tid][1];
        atomicMin(&keys[m0 + tid], a < b ? a : b);
    }
}

// ---------------------------------------------------------------------------
// Gather chosen code (fp32 exact), update residual, write bf16 residual,
// accumulate sum(resid_new^2).
// ---------------------------------------------------------------------------
__global__ __launch_bounds__(256) void vq_update_k(
    float* __restrict__ resid, u16* __restrict__ rbf,
    const float* __restrict__ E,
    const u64* __restrict__ keys, double* __restrict__ acc)
{
    __shared__ float red[4];
    const int tid = threadIdx.x;
    const int base = blockIdx.x * 16;
    float lsum = 0.f;
    for (int r = 0; r < 16; ++r) {
        const int row = base + r;
        const int idx = (int)(keys[row] & 0xFFFFFFFFull);
        const float q = E[(size_t)idx * LAT + tid];
        float v = resid[(size_t)row * LAT + tid] - q;
        resid[(size_t)row * LAT + tid] = v;
        rbf[(size_t)row * LAT + tid] = f2bf(v);
        lsum = fmaf(v, v, lsum);
    }
#pragma unroll
    for (int off = 32; off >= 1; off >>= 1) lsum += __shfl_xor(lsum, off);
    if ((tid & 63) == 0) red[tid >> 6] = lsum;
    __syncthreads();
    if (tid == 0) atomicAdd(acc, (double)(red[0] + red[1] + red[2] + red[3]));
}

__global__ void zero_k(double* __restrict__ acc) { acc[threadIdx.x] = 0.0; }

__global__ void finalize_k(const double* __restrict__ acc, float* __restrict__ out) {
    double total = 1.5 * acc[0] / (double)((size_t)N_ROWS * LAT)
                 + 0.5 * acc[1] / (double)((size_t)N_ROWS * OBS);
    out[0] = (float)total;
}

// ---------------------------------------------------------------------------
extern "C" void kernel_launch(void* const* d_in, const int* in_sizes, int n_in,
                              void* d_out, int out_size, void* d_ws, size_t ws_size,
                              hipStream_t stream)
{
    const float* x      = (const float*)d_in[0];
    const float* cb     = (const float*)d_in[1];
    const float* enc_w1 = (const float*)d_in[2];
    const float* enc_b1 = (const float*)d_in[3];
    const float* ln_g   = (const float*)d_in[4];
    const float* ln_b   = (const float*)d_in[5];
    const float* enc_w2 = (const float*)d_in[6];
    const float* enc_b2 = (const float*)d_in[7];
    const float* dec_w1 = (const float*)d_in[8];
    const float* dec_b1 = (const float*)d_in[9];
    const float* dec_w2 = (const float*)d_in[10];
    const float* dec_b2 = (const float*)d_in[11];

    char* ws = (char*)d_ws;
    const size_t MB = 1ull << 20;
    // Region A (64MB): h_bf (GEMM1->GEMM2), then dh_bf (GEMM3->GEMM4)
    u16* hbuf = (u16*)ws;
    // Region B (32MB): x_bf (conv->GEMM1); afterwards cbb(16)+rbf(8)+qbf(8)
    u16* xbf = (u16*)(ws + 64 * MB);
    u16* cbb = (u16*)(ws + 64 * MB);
    u16* rbf = (u16*)(ws + 80 * MB);
    u16* qbf = (u16*)(ws + 88 * MB);
    float* latent = (float*)(ws + 96 * MB);
    float* resid  = (float*)(ws + 112 * MB);
    u16* w1T  = (u16*)(ws + 128 * MB);   // [2048,1024]
    u16* w2T  = (u16*)(ws + 132 * MB);   // [256,2048]
    u16* wd1T = (u16*)(ws + 133 * MB);   // [2048,256]
    u16* wd2T = (u16*)(ws + 134 * MB);   // [1024,2048]
    float* enorm = (float*)(ws + 138 * MB);
    u64*   keys  = (u64*)(ws + 138 * MB + 131072);
    double* accs = (double*)(ws + 138 * MB + 262144);

    zero_k<<<1, 2, 0, stream>>>(accs);
    enorm_k<<<HQ * VOCAB / 4, 256, 0, stream>>>(cb, enorm);

    // weight transposes + x conversion
    tpose_bf_k<<<dim3(HID / 32, OBS / 32), 256, 0, stream>>>(enc_w1, w1T, OBS, HID);
    tpose_bf_k<<<dim3(LAT / 32, HID / 32), 256, 0, stream>>>(enc_w2, w2T, HID, LAT);
    tpose_bf_k<<<dim3(HID / 32, LAT / 32), 256, 0, stream>>>(dec_w1, wd1T, LAT, HID);
    tpose_bf_k<<<dim3(OBS / 32, HID / 32), 256, 0, stream>>>(dec_w2, wd2T, HID, OBS);
    f2bf_k<<<(int)((size_t)N_ROWS * OBS / 1024), 256, 0, stream>>>(x, xbf);

    // encoder: GEMM1 -> LN+ReLU -> GEMM2
    mfma_gemm_k<0><<<dim3(N_ROWS / 128, HID / 128), 256, 0, stream>>>(
        xbf, w1T, enc_b1, hbuf, nullptr, nullptr, nullptr, nullptr, nullptr, OBS, HID);
    ln_relu_bf_k<<<N_ROWS, 256, 0, stream>>>(hbuf, ln_g, ln_b);
    mfma_gemm_k<2><<<dim3(N_ROWS / 128, LAT / 128), 256, 0, stream>>>(
        hbuf, w2T, enc_b2, nullptr, latent, resid, rbf, nullptr, nullptr, HID, LAT);

    // bf16 codebooks (x_bf region now dead)
    f2bf_k<<<(int)((size_t)HQ * VOCAB * LAT / 1024), 256, 0, stream>>>(cb, cbb);

    for (int l = 0; l < HQ; ++l) {
        init_keys_k<<<N_ROWS / 256, 256, 0, stream>>>(keys);
        dist_mfma_k<<<dim3(N_ROWS / 128, VOCAB / 128), 256, 0, stream>>>(
            rbf, cbb + (size_t)l * VOCAB * LAT, enorm + (size_t)l * VOCAB, keys);
        vq_update_k<<<N_ROWS / 16, 256, 0, stream>>>(
            resid, rbf, cb + (size_t)l * VOCAB * LAT, keys, accs);
    }

    // quant -> decoder GEMM3 -> GEMM4(+loss)
    quant_bf_k<<<(int)((size_t)N_ROWS * LAT / 1024), 256, 0, stream>>>(latent, resid, qbf);
    mfma_gemm_k<1><<<dim3(N_ROWS / 128, HID / 128), 256, 0, stream>>>(
        qbf, wd1T, dec_b1, hbuf, nullptr, nullptr, nullptr, nullptr, nullptr, LAT, HID);
    mfma_gemm_k<3><<<dim3(N_ROWS / 128, OBS / 128), 256, 0, stream>>>(
        hbuf, wd2T, dec_b2, nullptr, nullptr, nullptr, nullptr, x, accs + 1, HID, OBS);

    finalize_k<<<1, 1, 0, stream>>>(accs, (float*)d_out);
}